// Round 1
// baseline (12500.334 us; speedup 1.0000x reference)
//
#include <hip/hip_runtime.h>
#include <hip/hip_bf16.h>
#include <math.h>

// Model dims
#define Bq   16
#define Tq   128
#define Hq   512
#define Dq   256
#define G4H  2048            // 4*H
#define MR   2048            // B*T rows
#define VO   32001           // VOUT+1
#define NPAD 32128           // VO padded to multiple of 128

typedef unsigned int u32;
typedef __attribute__((ext_vector_type(4))) float f32x4;
typedef __attribute__((ext_vector_type(8))) short bfrag;   // 8 x bf16 (4 VGPRs)
typedef __attribute__((ext_vector_type(4))) float facc;    // mfma accumulator

__device__ __forceinline__ float bf2f(short s) {
  union { unsigned u; float f; } v; v.u = ((unsigned)(unsigned short)s) << 16; return v.f;
}
__device__ __forceinline__ short f2bf(float f) {
  union { float f; unsigned u; } v; v.f = f;
  unsigned r = (v.u + 0x7fffu + ((v.u >> 16) & 1u)) >> 16;
  return (short)r;
}
__device__ __forceinline__ float sigm(float x) { return 1.0f / (1.0f + expf(-x)); }

// ---------------- device-scope grid barrier (grid co-resident: 128 blocks) ----
__device__ __forceinline__ void gbar(u32* cnt, u32* gen, u32 nb) {
  __syncthreads();
  if (threadIdx.x == 0) {
    __threadfence();
    u32 g = __hip_atomic_load(gen, __ATOMIC_RELAXED, __HIP_MEMORY_SCOPE_AGENT);
    u32 a = __hip_atomic_fetch_add(cnt, 1u, __ATOMIC_ACQ_REL, __HIP_MEMORY_SCOPE_AGENT);
    if (a == nb - 1u) {
      __hip_atomic_store(cnt, 0u, __ATOMIC_RELAXED, __HIP_MEMORY_SCOPE_AGENT);
      __hip_atomic_fetch_add(gen, 1u, __ATOMIC_RELEASE, __HIP_MEMORY_SCOPE_AGENT);
    } else {
      while (__hip_atomic_load(gen, __ATOMIC_ACQUIRE, __HIP_MEMORY_SCOPE_AGENT) == g) {
        __builtin_amdgcn_s_sleep(1);
      }
    }
    __threadfence();
  }
  __syncthreads();
}

// ---------------- transpose + f32->bf16:  in[R,N] -> out[NpadR,R], pad rows zero
__global__ __launch_bounds__(256) void k_transcvt(const float* __restrict__ in,
                                                  short* __restrict__ out,
                                                  int R, int N, int NpadR) {
  __shared__ float tile[32][33];
  int nb = blockIdx.x * 32, rb = blockIdx.y * 32;
  int tx = threadIdx.x & 31, ty = threadIdx.x >> 5;
  for (int i = 0; i < 4; ++i) {
    int r = rb + ty + i * 8;
    int n = nb + tx;
    tile[ty + i * 8][tx] = (n < N) ? in[(size_t)r * N + n] : 0.0f;
  }
  __syncthreads();
  for (int i = 0; i < 4; ++i) {
    int orow = nb + ty + i * 8;   // < NpadR by grid
    out[(size_t)orow * R + rb + tx] = f2bf(tile[tx][ty + i * 8]);
  }
}

// ---------------- flat f32 -> bf16
__global__ __launch_bounds__(256) void k_cvt(const float* __restrict__ in,
                                             short* __restrict__ out, int n) {
  int i = (blockIdx.x * 256 + threadIdx.x) * 4;
  if (i + 3 < n) {
    f32x4 v = *(const f32x4*)(in + i);
    short4 o;
    o.x = f2bf(v[0]); o.y = f2bf(v[1]); o.z = f2bf(v[2]); o.w = f2bf(v[3]);
    *(short4*)(out + i) = o;
  } else {
    for (int j = i; j < n; ++j) out[j] = f2bf(in[j]);
  }
}

// ---------------- embedding gather -> x_bf [T,B,D] bf16
__global__ __launch_bounds__(256) void k_gather(const int* __restrict__ tokens,
                                                const float* __restrict__ emb,
                                                short* __restrict__ xbf) {
  int row = blockIdx.x;                 // t*16+b
  int t = row >> 4, b = row & 15;
  int tok = tokens[b * Tq + t];
  xbf[(size_t)row * Dq + threadIdx.x] = f2bf(emb[(size_t)tok * Dq + threadIdx.x]);
}

// ---------------- bf16 MFMA GEMM: C[M,ldc] = A[M,K] @ BT[Npad,K]^T + bias
// 128x128 tile, BK=64, 4 waves (2x2 of 64x64), global_load_lds(16) staging,
// XOR chunk swizzle (q ^ (r&7)) for conflict-free ds_read_b128.
__global__ __launch_bounds__(256) void k_gemm(const short* __restrict__ A,
                                              const short* __restrict__ BT,
                                              float* __restrict__ C,
                                              const float* __restrict__ bias,
                                              int M, int Nreal, int K, int ldc) {
  __shared__ short lA[128 * 64];
  __shared__ short lB[128 * 64];
  const int tid = threadIdx.x;
  const int wave = tid >> 6, lane = tid & 63;
  const int l15 = lane & 15, l4 = lane >> 4;
  const int m0 = blockIdx.y * 128, n0 = blockIdx.x * 128;
  const int wm = (wave >> 1) * 64, wn = (wave & 1) * 64;
  facc acc[4][4] = {};

  for (int k0 = 0; k0 < K; k0 += 64) {
    __syncthreads();
    for (int i = 0; i < 4; ++i) {
      int c = i * 256 + wave * 64 + lane;
      int r = c >> 3, q = c & 7;
      int qs = q ^ (r & 7);
      const short* ga = A + (size_t)(m0 + r) * K + k0 + qs * 8;
      const short* gb = BT + (size_t)(n0 + r) * K + k0 + qs * 8;
      short* la = lA + (size_t)(i * 256 + wave * 64) * 8;
      short* lb = lB + (size_t)(i * 256 + wave * 64) * 8;
      __builtin_amdgcn_global_load_lds((const __attribute__((address_space(1))) u32*)ga,
                                       (__attribute__((address_space(3))) u32*)la, 16, 0, 0);
      __builtin_amdgcn_global_load_lds((const __attribute__((address_space(1))) u32*)gb,
                                       (__attribute__((address_space(3))) u32*)lb, 16, 0, 0);
    }
    __syncthreads();
    for (int ks = 0; ks < 2; ++ks) {
      bfrag a[4], b[4];
      for (int mi = 0; mi < 4; ++mi) {
        int r = wm + mi * 16 + l15;
        int qs = (ks * 4 + l4) ^ (r & 7);
        a[mi] = *(const bfrag*)&lA[r * 64 + qs * 8];
      }
      for (int ni = 0; ni < 4; ++ni) {
        int r = wn + ni * 16 + l15;
        int qs = (ks * 4 + l4) ^ (r & 7);
        b[ni] = *(const bfrag*)&lB[r * 64 + qs * 8];
      }
      for (int mi = 0; mi < 4; ++mi)
        for (int ni = 0; ni < 4; ++ni)
          acc[mi][ni] = __builtin_amdgcn_mfma_f32_16x16x32_bf16(a[mi], b[ni], acc[mi][ni], 0, 0, 0);
    }
  }
  for (int ni = 0; ni < 4; ++ni) {
    int col = n0 + wn + ni * 16 + l15;
    if (col >= Nreal) continue;
    float bs = bias ? bias[col] : 0.0f;
    for (int mi = 0; mi < 4; ++mi) {
      int rb = m0 + wm + mi * 16 + l4 * 4;
      facc v = acc[mi][ni];
      C[(size_t)(rb + 0) * ldc + col] = v[0] + bs;
      C[(size_t)(rb + 1) * ldc + col] = v[1] + bs;
      C[(size_t)(rb + 2) * ldc + col] = v[2] + bs;
      C[(size_t)(rb + 3) * ldc + col] = v[3] + bs;
    }
  }
}

// ---------------- LSTM encoder layer (persistent, 128 blocks x 512 thr)
// z = XW[t*16+b] + h @ U^T (UT bf16 [2048,512]); gates; writes seq [T,B,H].
__global__ __launch_bounds__(512) void k_enc(const float* __restrict__ XW,
                                             const short* __restrict__ UT,
                                             float* __restrict__ h_g, float* __restrict__ c_g,
                                             const float* __restrict__ hinit,
                                             const float* __restrict__ cinit,
                                             float* __restrict__ seq,
                                             u32* cnt, u32* gen) {
  __shared__ float lh[Bq * Hq];
  __shared__ float zbuf[512];
  const int tid = threadIdx.x;
  const int n0 = blockIdx.x * 4;
  const int tt = tid & 255, kh = tid >> 8;
  const int nl = tt & 3, g = (tt >> 2) & 3, b = tt >> 4;
  const int col = g * Hq + n0 + nl;

  if (tid < 64) {
    int bb = tid >> 2, nn = n0 + (tid & 3);
    h_g[bb * Hq + nn] = hinit ? hinit[bb * Hq + nn] : 0.0f;
    c_g[bb * Hq + nn] = cinit ? cinit[bb * Hq + nn] : 0.0f;
  }
  gbar(cnt, gen, gridDim.x);

  const short* urow = UT + (size_t)col * Hq + kh * 256;
  for (int s = 0; s < Tq; ++s) {
    { // stage h into LDS
      const f32x4* hv = (const f32x4*)h_g;
      f32x4* lv = (f32x4*)lh;
      for (int i = tid; i < (Bq * Hq / 4); i += 512) lv[i] = hv[i];
    }
    __syncthreads();
    float acc = 0.0f;
    const float* hrow = lh + b * Hq + kh * 256;
    #pragma unroll 4
    for (int k = 0; k < 256; k += 8) {
      bfrag u = *(const bfrag*)(urow + k);
      f32x4 h0 = *(const f32x4*)(hrow + k);
      f32x4 h1 = *(const f32x4*)(hrow + k + 4);
      acc += bf2f(u[0]) * h0[0] + bf2f(u[1]) * h0[1] + bf2f(u[2]) * h0[2] + bf2f(u[3]) * h0[3]
           + bf2f(u[4]) * h1[0] + bf2f(u[5]) * h1[1] + bf2f(u[6]) * h1[2] + bf2f(u[7]) * h1[3];
    }
    zbuf[tid] = acc;
    __syncthreads();
    if (tid < 64) {
      int bb = tid >> 2, nn = tid & 3;
      int zb = bb * 16 + nn;
      const float* xwr = XW + (size_t)(s * Bq + bb) * G4H;
      float zi = zbuf[zb + 0]  + zbuf[256 + zb + 0]  + xwr[0 * Hq + n0 + nn];
      float zf = zbuf[zb + 4]  + zbuf[256 + zb + 4]  + xwr[1 * Hq + n0 + nn];
      float zg = zbuf[zb + 8]  + zbuf[256 + zb + 8]  + xwr[2 * Hq + n0 + nn];
      float zo = zbuf[zb + 12] + zbuf[256 + zb + 12] + xwr[3 * Hq + n0 + nn];
      int idx = bb * Hq + n0 + nn;
      float cN = sigm(zf) * c_g[idx] + sigm(zi) * tanhf(zg);
      float hN = sigm(zo) * tanhf(cN);
      c_g[idx] = cN;
      h_g[idx] = hN;
      seq[(size_t)(s * Bq + bb) * Hq + n0 + nn] = hN;
    }
    gbar(cnt, gen, gridDim.x);
  }
}

// ---------------- decoder: 2 LSTM cells per step (attention deferred)
__global__ __launch_bounds__(512) void k_dec(const float* __restrict__ XW,
                                             const short* __restrict__ Ud1T,
                                             const short* __restrict__ Wd2T,
                                             const short* __restrict__ Ud2T,
                                             const float* __restrict__ bd2,
                                             const float* __restrict__ h1, const float* __restrict__ c1,
                                             const float* __restrict__ h2, const float* __restrict__ c2,
                                             float* __restrict__ hA, float* __restrict__ cA,
                                             float* __restrict__ hB, float* __restrict__ cB,
                                             float* __restrict__ hBseq, float* __restrict__ dec,
                                             u32* cnt, u32* gen) {
  __shared__ float lha[Bq * Hq];
  __shared__ float lhb[Bq * Hq];
  __shared__ float zbuf[512];
  const int tid = threadIdx.x;
  const int n0 = blockIdx.x * 4;
  const int tt = tid & 255, kh = tid >> 8;
  const int nl = tt & 3, g = (tt >> 2) & 3, b = tt >> 4;
  const int col = g * Hq + n0 + nl;

  if (tid < 64) {
    int bb = tid >> 2, nn = n0 + (tid & 3);
    int idx = bb * Hq + nn;
    hA[idx] = h1[idx]; cA[idx] = c1[idx];
    hB[idx] = h2[idx]; cB[idx] = c2[idx];
  }
  gbar(cnt, gen, gridDim.x);

  const short* u1row = Ud1T + (size_t)col * Hq + kh * 256;
  const short* w2row = Wd2T + (size_t)col * Hq + kh * 256;
  const short* u2row = Ud2T + (size_t)col * Hq + kh * 256;

  for (int s = 0; s < Tq; ++s) {
    // ---- phase A: hA,cA = cell(seq2[s], hA, cA)
    {
      const f32x4* hv = (const f32x4*)hA;
      f32x4* lv = (f32x4*)lha;
      for (int i = tid; i < (Bq * Hq / 4); i += 512) lv[i] = hv[i];
    }
    __syncthreads();
    float acc = 0.0f;
    {
      const float* hrow = lha + b * Hq + kh * 256;
      #pragma unroll 4
      for (int k = 0; k < 256; k += 8) {
        bfrag u = *(const bfrag*)(u1row + k);
        f32x4 h0 = *(const f32x4*)(hrow + k);
        f32x4 h1v = *(const f32x4*)(hrow + k + 4);
        acc += bf2f(u[0]) * h0[0] + bf2f(u[1]) * h0[1] + bf2f(u[2]) * h0[2] + bf2f(u[3]) * h0[3]
             + bf2f(u[4]) * h1v[0] + bf2f(u[5]) * h1v[1] + bf2f(u[6]) * h1v[2] + bf2f(u[7]) * h1v[3];
      }
    }
    zbuf[tid] = acc;
    __syncthreads();
    if (tid < 64) {
      int bb = tid >> 2, nn = tid & 3;
      int zb = bb * 16 + nn;
      const float* xwr = XW + (size_t)(s * Bq + bb) * G4H;
      float zi = zbuf[zb + 0]  + zbuf[256 + zb + 0]  + xwr[0 * Hq + n0 + nn];
      float zf = zbuf[zb + 4]  + zbuf[256 + zb + 4]  + xwr[1 * Hq + n0 + nn];
      float zg = zbuf[zb + 8]  + zbuf[256 + zb + 8]  + xwr[2 * Hq + n0 + nn];
      float zo = zbuf[zb + 12] + zbuf[256 + zb + 12] + xwr[3 * Hq + n0 + nn];
      int idx = bb * Hq + n0 + nn;
      float cN = sigm(zf) * cA[idx] + sigm(zi) * tanhf(zg);
      float hN = sigm(zo) * tanhf(cN);
      cA[idx] = cN;
      hA[idx] = hN;
    }
    gbar(cnt, gen, gridDim.x);

    // ---- phase B: hB,cB = cell(hA_new, hB, cB)
    {
      const f32x4* av = (const f32x4*)hA;
      const f32x4* bv = (const f32x4*)hB;
      f32x4* la = (f32x4*)lha;
      f32x4* lb = (f32x4*)lhb;
      for (int i = tid; i < (Bq * Hq / 4); i += 512) { la[i] = av[i]; lb[i] = bv[i]; }
    }
    __syncthreads();
    acc = 0.0f;
    {
      const float* arow = lha + b * Hq + kh * 256;
      const float* brow = lhb + b * Hq + kh * 256;
      #pragma unroll 2
      for (int k = 0; k < 256; k += 8) {
        bfrag u = *(const bfrag*)(w2row + k);
        f32x4 a0 = *(const f32x4*)(arow + k);
        f32x4 a1 = *(const f32x4*)(arow + k + 4);
        acc += bf2f(u[0]) * a0[0] + bf2f(u[1]) * a0[1] + bf2f(u[2]) * a0[2] + bf2f(u[3]) * a0[3]
             + bf2f(u[4]) * a1[0] + bf2f(u[5]) * a1[1] + bf2f(u[6]) * a1[2] + bf2f(u[7]) * a1[3];
        bfrag w = *(const bfrag*)(u2row + k);
        f32x4 b0 = *(const f32x4*)(brow + k);
        f32x4 b1v = *(const f32x4*)(brow + k + 4);
        acc += bf2f(w[0]) * b0[0] + bf2f(w[1]) * b0[1] + bf2f(w[2]) * b0[2] + bf2f(w[3]) * b0[3]
             + bf2f(w[4]) * b1v[0] + bf2f(w[5]) * b1v[1] + bf2f(w[6]) * b1v[2] + bf2f(w[7]) * b1v[3];
      }
    }
    zbuf[tid] = acc;
    __syncthreads();
    if (tid < 64) {
      int bb = tid >> 2, nn = tid & 3;
      int zb = bb * 16 + nn;
      int n = n0 + nn;
      float zi = zbuf[zb + 0]  + zbuf[256 + zb + 0]  + bd2[0 * Hq + n];
      float zf = zbuf[zb + 4]  + zbuf[256 + zb + 4]  + bd2[1 * Hq + n];
      float zg = zbuf[zb + 8]  + zbuf[256 + zb + 8]  + bd2[2 * Hq + n];
      float zo = zbuf[zb + 12] + zbuf[256 + zb + 12] + bd2[3 * Hq + n];
      int idx = bb * Hq + n;
      float cN = sigm(zf) * cB[idx] + sigm(zi) * tanhf(zg);
      float hN = sigm(zo) * tanhf(cN);
      cB[idx] = cN;
      hB[idx] = hN;
      hBseq[(size_t)(s * Bq + bb) * Hq + n] = hN;
      dec[(size_t)(bb * Tq + s) * (2 * Hq) + n] = hN;   // first half of decoder output
    }
    gbar(cnt, gen, gridDim.x);
  }
}

// ---------------- batched attention over full seq2 (one block per (b,t))
__global__ __launch_bounds__(256) void k_attn(const float* __restrict__ seq2,
                                              const float* __restrict__ hBseq,
                                              float* __restrict__ dec) {
  int blk = blockIdx.x;
  int b = blk >> 7, t = blk & 127;
  __shared__ float q[Hq];
  __shared__ float part[256];
  __shared__ float p[Tq];
  int tid = threadIdx.x;
  const float* qsrc = hBseq + (size_t)(t * Bq + b) * Hq;
  q[tid] = qsrc[tid]; q[tid + 256] = qsrc[tid + 256];
  __syncthreads();
  {
    int s = tid >> 1, half = tid & 1;
    const float* row = seq2 + (size_t)(s * Bq + b) * Hq + half * 256;
    const float* qh = q + half * 256;
    float a = 0.0f;
    for (int k = 0; k < 256; k += 4) {
      f32x4 r4 = *(const f32x4*)(row + k);
      f32x4 q4 = *(const f32x4*)(qh + k);
      a += r4[0] * q4[0] + r4[1] * q4[1] + r4[2] * q4[2] + r4[3] * q4[3];
    }
    part[tid] = a;
  }
  __syncthreads();
  if (tid < 64) {
    float v0 = part[2 * tid] + part[2 * tid + 1];
    float v1 = part[2 * (tid + 64)] + part[2 * (tid + 64) + 1];
    float mx = fmaxf(v0, v1);
    for (int off = 32; off; off >>= 1) mx = fmaxf(mx, __shfl_xor(mx, off));
    float e0 = __expf(v0 - mx), e1 = __expf(v1 - mx);
    float sm = e0 + e1;
    for (int off = 32; off; off >>= 1) sm += __shfl_xor(sm, off);
    float inv = 1.0f / sm;
    p[tid] = e0 * inv; p[tid + 64] = e1 * inv;
  }
  __syncthreads();
  float c0 = 0.0f, c1 = 0.0f;
  for (int s = 0; s < Tq; ++s) {
    float ps = p[s];
    const float* row = seq2 + (size_t)(s * Bq + b) * Hq;
    c0 += ps * row[tid];
    c1 += ps * row[tid + 256];
  }
  float* drow = dec + (size_t)(b * Tq + t) * (2 * Hq) + Hq;
  drow[tid] = c0; drow[tid + 256] = c1;
}

// ---------------- row softmax over VO=32001 (in-place on d_out)
__global__ __launch_bounds__(256) void k_softmax(float* __restrict__ L) {
  int row = blockIdx.x;
  float* p = L + (size_t)row * VO;
  int tid = threadIdx.x;
  float m = -3.0e38f, s = 0.0f;
  for (int i = tid; i < VO; i += 256) {
    float v = p[i];
    float mn = fmaxf(m, v);
    s = s * __expf(m - mn) + __expf(v - mn);
    m = mn;
  }
  __shared__ float sm[256], ss[256];
  sm[tid] = m; ss[tid] = s;
  __syncthreads();
  for (int off = 128; off; off >>= 1) {
    if (tid < off) {
      float m2 = sm[tid + off], s2 = ss[tid + off];
      float mn = fmaxf(sm[tid], m2);
      ss[tid] = ss[tid] * __expf(sm[tid] - mn) + s2 * __expf(m2 - mn);
      sm[tid] = mn;
    }
    __syncthreads();
  }
  float M = sm[0], IS = 1.0f / ss[0];
  for (int i = tid; i < VO; i += 256) {
    p[i] = __expf(p[i] - M) * IS;
  }
}

// =============================================================================
extern "C" void kernel_launch(void* const* d_in, const int* in_sizes, int n_in,
                              void* d_out, int out_size, void* d_ws, size_t ws_size,
                              hipStream_t stream) {
  const int*   tokens = (const int*)d_in[0];
  const float* emb    = (const float*)d_in[1];
  const float* W1     = (const float*)d_in[2];
  const float* U1     = (const float*)d_in[3];
  const float* b1     = (const float*)d_in[4];
  const float* W2     = (const float*)d_in[5];
  const float* U2     = (const float*)d_in[6];
  const float* b2     = (const float*)d_in[7];
  const float* Wd1    = (const float*)d_in[8];
  const float* Ud1    = (const float*)d_in[9];
  const float* bd1    = (const float*)d_in[10];
  const float* Wd2    = (const float*)d_in[11];
  const float* Ud2    = (const float*)d_in[12];
  const float* bd2    = (const float*)d_in[13];
  const float* Wo     = (const float*)d_in[14];
  const float* bo     = (const float*)d_in[15];
  float* out = (float*)d_out;

  // ---- workspace layout (~123 MB)
  size_t off = 0;
  char* base = (char*)d_ws;
  auto alloc = [&](size_t bytes) -> void* {
    void* p = base + off;
    off += (bytes + 255) & ~(size_t)255;
    return p;
  };
  u32*   bar     = (u32*)alloc(256);              // [0]=cnt, [32]=gen (separate lines)
  short* x_bf    = (short*)alloc((size_t)MR * Dq * 2);
  short* W1T     = (short*)alloc((size_t)G4H * Dq * 2);
  short* W2T     = (short*)alloc((size_t)G4H * Hq * 2);
  short* Wd1T    = (short*)alloc((size_t)G4H * Hq * 2);
  short* WoT     = (short*)alloc((size_t)NPAD * (2 * Hq) * 2);
  short* U1T     = (short*)alloc((size_t)G4H * Hq * 2);
  short* U2T     = (short*)alloc((size_t)G4H * Hq * 2);
  short* Ud1T    = (short*)alloc((size_t)G4H * Hq * 2);
  short* Ud2T    = (short*)alloc((size_t)G4H * Hq * 2);
  short* Wd2T    = (short*)alloc((size_t)G4H * Hq * 2);
  float* XW      = (float*)alloc((size_t)MR * G4H * 4);
  float* seq1    = (float*)alloc((size_t)MR * Hq * 4);
  float* seq2    = (float*)alloc((size_t)MR * Hq * 4);
  short* seq1_bf = (short*)alloc((size_t)MR * Hq * 2);
  short* seq2_bf = (short*)alloc((size_t)MR * Hq * 2);
  float* hBseq   = (float*)alloc((size_t)MR * Hq * 4);
  float* dec     = (float*)alloc((size_t)MR * 2 * Hq * 4);
  short* dec_bf  = (short*)alloc((size_t)MR * 2 * Hq * 2);
  float* h1 = (float*)alloc(Bq * Hq * 4);
  float* c1 = (float*)alloc(Bq * Hq * 4);
  float* h2 = (float*)alloc(Bq * Hq * 4);
  float* c2 = (float*)alloc(Bq * Hq * 4);
  float* hA = (float*)alloc(Bq * Hq * 4);
  float* cA = (float*)alloc(Bq * Hq * 4);
  float* hB = (float*)alloc(Bq * Hq * 4);
  float* cB = (float*)alloc(Bq * Hq * 4);
  u32* cnt = bar;
  u32* gen = bar + 32;
  (void)ws_size; (void)in_sizes; (void)n_in; (void)out_size; (void)bd1;

  hipMemsetAsync(bar, 0, 256, stream);

  // weight transposes + bf16 conversion
  k_transcvt<<<dim3(G4H / 32, Dq / 32), 256, 0, stream>>>(W1, W1T, Dq, G4H, G4H);
  k_transcvt<<<dim3(G4H / 32, Hq / 32), 256, 0, stream>>>(W2, W2T, Hq, G4H, G4H);
  k_transcvt<<<dim3(G4H / 32, Hq / 32), 256, 0, stream>>>(Wd1, Wd1T, Hq, G4H, G4H);
  k_transcvt<<<dim3(G4H / 32, Hq / 32), 256, 0, stream>>>(U1, U1T, Hq, G4H, G4H);
  k_transcvt<<<dim3(G4H / 32, Hq / 32), 256, 0, stream>>>(U2, U2T, Hq, G4H, G4H);
  k_transcvt<<<dim3(G4H / 32, Hq / 32), 256, 0, stream>>>(Ud1, Ud1T, Hq, G4H, G4H);
  k_transcvt<<<dim3(G4H / 32, Hq / 32), 256, 0, stream>>>(Ud2, Ud2T, Hq, G4H, G4H);
  k_transcvt<<<dim3(G4H / 32, Hq / 32), 256, 0, stream>>>(Wd2, Wd2T, Hq, G4H, G4H);
  k_transcvt<<<dim3(NPAD / 32, (2 * Hq) / 32), 256, 0, stream>>>(Wo, WoT, 2 * Hq, VO, NPAD);

  // embedding gather
  k_gather<<<MR, 256, 0, stream>>>(tokens, emb, x_bf);

  // encoder layer 1
  k_gemm<<<dim3(G4H / 128, MR / 128), 256, 0, stream>>>(x_bf, W1T, XW, b1, MR, G4H, Dq, G4H);
  k_enc<<<128, 512, 0, stream>>>(XW, U1T, h1, c1, nullptr, nullptr, seq1, cnt, gen);

  // encoder layer 2 (init from layer-1 finals)
  k_cvt<<<(MR * Hq) / 1024, 256, 0, stream>>>(seq1, seq1_bf, MR * Hq);
  k_gemm<<<dim3(G4H / 128, MR / 128), 256, 0, stream>>>(seq1_bf, W2T, XW, b2, MR, G4H, Hq, G4H);
  k_enc<<<128, 512, 0, stream>>>(XW, U2T, h2, c2, h1, c1, seq2, cnt, gen);

  // decoder (input = seq2; carries init from (h1,c1),(h2,c2))
  k_cvt<<<(MR * Hq) / 1024, 256, 0, stream>>>(seq2, seq2_bf, MR * Hq);
  k_gemm<<<dim3(G4H / 128, MR / 128), 256, 0, stream>>>(seq2_bf, Wd1T, XW, bd1, MR, G4H, Hq, G4H);
  k_dec<<<128, 512, 0, stream>>>(XW, Ud1T, Wd2T, Ud2T, bd2,
                                 h1, c1, h2, c2, hA, cA, hB, cB, hBseq, dec, cnt, gen);

  // attention (batched over all t; out never feeds the recurrence)
  k_attn<<<MR, 256, 0, stream>>>(seq2, hBseq, dec);

  // logits GEMM + softmax
  k_cvt<<<(MR * 2 * Hq) / 1024, 256, 0, stream>>>(dec, dec_bf, MR * 2 * Hq);
  k_gemm<<<dim3(NPAD / 128, MR / 128), 256, 0, stream>>>(dec_bf, WoT, out, bo, MR, VO, 2 * Hq, VO);
  k_softmax<<<MR, 256, 0, stream>>>(out);
}

// Round 2
// 3723.024 us; speedup vs baseline: 3.3576x; 3.3576x over previous
//
#include <hip/hip_runtime.h>
#include <hip/hip_bf16.h>
#include <math.h>

// Model dims
#define Bq   16
#define Tq   128
#define Hq   512
#define Dq   256
#define G4H  2048            // 4*H
#define MR   2048            // B*T rows
#define VO   32001           // VOUT+1
#define NPAD 32128           // VO padded to multiple of 128
#define NBLK 32              // persistent blocks for recurrence
#define BH   (Bq * Hq)       // 8192

typedef unsigned int u32;
typedef __attribute__((ext_vector_type(4))) float f32x4;
typedef __attribute__((ext_vector_type(8))) short bfrag;   // 8 x bf16 (4 VGPRs)
typedef __attribute__((ext_vector_type(4))) float facc;    // mfma accumulator

__device__ __forceinline__ float bf2f(short s) {
  union { unsigned u; float f; } v; v.u = ((unsigned)(unsigned short)s) << 16; return v.f;
}
__device__ __forceinline__ short f2bf(float f) {
  union { float f; unsigned u; } v; v.f = f;
  unsigned r = (v.u + 0x7fffu + ((v.u >> 16) & 1u)) >> 16;
  return (short)r;
}
__device__ __forceinline__ float sigm(float x) { return 1.0f / (1.0f + expf(-x)); }

// ---------------- all-to-all flag barrier: 32 parallel stores, 32 parallel polls
// (round-1's single-counter barrier serialized 128 far-atomic RMWs -> 24us/phase)
__device__ __forceinline__ void flagbar(u32* flags, u32 phase) {
  __syncthreads();                       // block stores drained (vmcnt before barrier)
  const int tid = threadIdx.x;
  if (tid == 0) {
    __threadfence();                     // writeback so other XCDs see our h stores
    __hip_atomic_store(&flags[blockIdx.x * 32], phase, __ATOMIC_RELEASE, __HIP_MEMORY_SCOPE_AGENT);
  }
  if (tid < NBLK) {                      // wave0 lanes each poll one block's flag
    u32 v;
    do {
      v = __hip_atomic_load(&flags[tid * 32], __ATOMIC_ACQUIRE, __HIP_MEMORY_SCOPE_AGENT);
      if (v < phase) __builtin_amdgcn_s_sleep(2);
    } while (v < phase);
  }
  if (tid == 0) __threadfence();         // invalidate for fresh h reads
  __syncthreads();
}

// ---------------- transpose + f32->bf16 (+ optional gate-interleave col perm)
// in[R,N] -> out[perm(n)][R]; pad rows (n>=N) zero. perm: n' = (n%512)*4 + n/512.
__global__ __launch_bounds__(256) void k_transcvt(const float* __restrict__ in,
                                                  short* __restrict__ out,
                                                  int R, int N, int perm) {
  __shared__ float tile[32][33];
  int nb = blockIdx.x * 32, rb = blockIdx.y * 32;
  int tx = threadIdx.x & 31, ty = threadIdx.x >> 5;
  for (int i = 0; i < 4; ++i) {
    int r = rb + ty + i * 8;
    int n = nb + tx;
    tile[ty + i * 8][tx] = (n < N) ? in[(size_t)r * N + n] : 0.0f;
  }
  __syncthreads();
  for (int i = 0; i < 4; ++i) {
    int n = nb + ty + i * 8;
    int orow = perm ? (((n & 511) << 2) | (n >> 9)) : n;
    out[(size_t)orow * R + rb + tx] = f2bf(tile[tx][ty + i * 8]);
  }
}

// ---------------- flat f32 -> bf16
__global__ __launch_bounds__(256) void k_cvt(const float* __restrict__ in,
                                             short* __restrict__ out, int n) {
  int i = (blockIdx.x * 256 + threadIdx.x) * 4;
  if (i + 3 < n) {
    f32x4 v = *(const f32x4*)(in + i);
    short4 o;
    o.x = f2bf(v[0]); o.y = f2bf(v[1]); o.z = f2bf(v[2]); o.w = f2bf(v[3]);
    *(short4*)(out + i) = o;
  }
}

// ---------------- embedding gather -> x_bf [T*B, D] bf16
__global__ __launch_bounds__(256) void k_gather(const int* __restrict__ tokens,
                                                const float* __restrict__ emb,
                                                short* __restrict__ xbf) {
  int row = blockIdx.x;                 // t*16+b
  int t = row >> 4, b = row & 15;
  int tok = tokens[b * Tq + t];
  xbf[(size_t)row * Dq + threadIdx.x] = f2bf(emb[(size_t)tok * Dq + threadIdx.x]);
}

// ---------------- bf16 MFMA GEMM: C[M,ldc] = A[M,K] @ BT[Npad,K]^T + bias
__global__ __launch_bounds__(256) void k_gemm(const short* __restrict__ A,
                                              const short* __restrict__ BT,
                                              float* __restrict__ C,
                                              const float* __restrict__ bias,
                                              int M, int Nreal, int K, int ldc,
                                              int permb) {
  __shared__ short lA[128 * 64];
  __shared__ short lB[128 * 64];
  const int tid = threadIdx.x;
  const int wave = tid >> 6, lane = tid & 63;
  const int l15 = lane & 15, l4 = lane >> 4;
  const int m0 = blockIdx.y * 128, n0 = blockIdx.x * 128;
  const int wm = (wave >> 1) * 64, wn = (wave & 1) * 64;
  facc acc[4][4] = {};

  for (int k0 = 0; k0 < K; k0 += 64) {
    __syncthreads();
    for (int i = 0; i < 4; ++i) {
      int c = i * 256 + wave * 64 + lane;
      int r = c >> 3, q = c & 7;
      int qs = q ^ (r & 7);
      const short* ga = A + (size_t)(m0 + r) * K + k0 + qs * 8;
      const short* gb = BT + (size_t)(n0 + r) * K + k0 + qs * 8;
      short* la = lA + (size_t)(i * 256 + wave * 64) * 8;
      short* lb = lB + (size_t)(i * 256 + wave * 64) * 8;
      __builtin_amdgcn_global_load_lds((const __attribute__((address_space(1))) u32*)ga,
                                       (__attribute__((address_space(3))) u32*)la, 16, 0, 0);
      __builtin_amdgcn_global_load_lds((const __attribute__((address_space(1))) u32*)gb,
                                       (__attribute__((address_space(3))) u32*)lb, 16, 0, 0);
    }
    __syncthreads();
    for (int ks = 0; ks < 2; ++ks) {
      bfrag a[4], b[4];
      for (int mi = 0; mi < 4; ++mi) {
        int r = wm + mi * 16 + l15;
        int qs = (ks * 4 + l4) ^ (r & 7);
        a[mi] = *(const bfrag*)&lA[r * 64 + qs * 8];
      }
      for (int ni = 0; ni < 4; ++ni) {
        int r = wn + ni * 16 + l15;
        int qs = (ks * 4 + l4) ^ (r & 7);
        b[ni] = *(const bfrag*)&lB[r * 64 + qs * 8];
      }
      for (int mi = 0; mi < 4; ++mi)
        for (int ni = 0; ni < 4; ++ni)
          acc[mi][ni] = __builtin_amdgcn_mfma_f32_16x16x32_bf16(a[mi], b[ni], acc[mi][ni], 0, 0, 0);
    }
  }
  for (int ni = 0; ni < 4; ++ni) {
    int col = n0 + wn + ni * 16 + l15;
    if (col >= Nreal) continue;
    int bcol = permb ? (((col & 3) << 9) | (col >> 2)) : col;
    float bs = bias ? bias[bcol] : 0.0f;
    for (int mi = 0; mi < 4; ++mi) {
      int rb = m0 + wm + mi * 16 + l4 * 4;
      facc v = acc[mi][ni];
      C[(size_t)(rb + 0) * ldc + col] = v[0] + bs;
      C[(size_t)(rb + 1) * ldc + col] = v[1] + bs;
      C[(size_t)(rb + 2) * ldc + col] = v[2] + bs;
      C[(size_t)(rb + 3) * ldc + col] = v[3] + bs;
    }
  }
}

// ---------------- single-cell LSTM recurrence (persistent, NBLK x 256)
// UT is gate-interleaved [2048 cols'][512] bf16; XW holds x@W+b in same col' layout.
// h state: global bf16 double-buffered (parity), hi/lo split for ~f32 matvec accuracy.
// Each wave owns 4 h-columns (all 4 gates); c lives in registers.
__global__ __launch_bounds__(256) void k_rec(const float* __restrict__ XW,
                                             const short* __restrict__ UT,
                                             const float* __restrict__ hinit,
                                             const float* __restrict__ cinit,
                                             short* __restrict__ hbuf,   // [2 par][2 hi/lo][BH]
                                             float* __restrict__ hfin,
                                             float* __restrict__ cfin,
                                             short* __restrict__ seq_bf,
                                             float* __restrict__ seq_f32,
                                             u32* flags) {
  __shared__ short lh[2][16][520];
  __shared__ float zt[4][16][20];
  const int tid = threadIdx.x;
  const int wv = tid >> 6, lane = tid & 63;
  const int l15 = lane & 15, l4 = lane >> 4;
  const int gw = blockIdx.x * 4 + wv;          // 0..127: owns h cols [4gw,4gw+4)
  const int bb = lane >> 2, jj = lane & 3;
  const int hidx = gw * 4 + jj;

  float c = cinit ? cinit[bb * Hq + hidx] : 0.0f;
  {
    float hv = hinit ? hinit[bb * Hq + hidx] : 0.0f;
    short hi_ = f2bf(hv), lo_ = f2bf(hv - bf2f(hi_));
    hbuf[0 * BH + bb * Hq + hidx] = hi_;
    hbuf[1 * BH + bb * Hq + hidx] = lo_;
  }
  flagbar(flags, 1);

  const short* ub = UT + (size_t)(gw * 16 + l15) * Hq + l4 * 8;

  for (int s = 0; s < Tq; ++s) {
    const short* hsrc = hbuf + (size_t)(s & 1) * 2 * BH;
    for (int i = tid; i < 2048; i += 256) {
      int part = i >> 10, rem = i & 1023, r = rem >> 6, o = (rem & 63) * 8;
      *(bfrag*)&lh[part][r][o] = *(const bfrag*)&hsrc[part * BH + r * Hq + o];
    }
    __syncthreads();
    facc a0 = {}, a1 = {};
    #pragma unroll
    for (int ks = 0; ks < 16; ++ks) {
      bfrag bu = *(const bfrag*)&ub[ks * 32];
      bfrag ah = *(const bfrag*)&lh[0][l15][ks * 32 + l4 * 8];
      bfrag al = *(const bfrag*)&lh[1][l15][ks * 32 + l4 * 8];
      a0 = __builtin_amdgcn_mfma_f32_16x16x32_bf16(ah, bu, a0, 0, 0, 0);
      a1 = __builtin_amdgcn_mfma_f32_16x16x32_bf16(al, bu, a1, 0, 0, 0);
    }
    a0 += a1;
    *(f32x4*)&zt[wv][l15][l4 * 4] = a0;
    __syncthreads();
    {
      f32x4 xg = *(const f32x4*)&XW[(size_t)(s * Bq + bb) * G4H + hidx * 4];
      float zi = zt[wv][4 * jj + 0][bb] + xg[0];
      float zf = zt[wv][4 * jj + 1][bb] + xg[1];
      float zg = zt[wv][4 * jj + 2][bb] + xg[2];
      float zo = zt[wv][4 * jj + 3][bb] + xg[3];
      c = sigm(zf) * c + sigm(zi) * tanhf(zg);
      float hN = sigm(zo) * tanhf(c);
      short hi_ = f2bf(hN), lo_ = f2bf(hN - bf2f(hi_));
      size_t np = (size_t)((s + 1) & 1) * 2 * BH;
      hbuf[np + bb * Hq + hidx] = hi_;
      hbuf[np + BH + bb * Hq + hidx] = lo_;
      seq_bf[(size_t)(s * Bq + bb) * Hq + hidx] = hi_;
      if (seq_f32) seq_f32[(size_t)(s * Bq + bb) * Hq + hidx] = hN;
      if (s == Tq - 1) { hfin[bb * Hq + hidx] = hN; cfin[bb * Hq + hidx] = c; }
    }
    flagbar(flags, (u32)(s + 2));
  }
}

// ---------------- decoder: cells A and B skewed (phase p: A(p) and B(p-1))
__global__ __launch_bounds__(256) void k_dec2(const float* __restrict__ XW,
                                              const short* __restrict__ U1T,   // Ud1'
                                              const short* __restrict__ W2T,   // Wd2'
                                              const short* __restrict__ U2T,   // Ud2'
                                              const float* __restrict__ bd2,
                                              const float* __restrict__ h1f, const float* __restrict__ c1f,
                                              const float* __restrict__ h2f, const float* __restrict__ c2f,
                                              short* __restrict__ hAbuf, short* __restrict__ hBbuf,
                                              float* __restrict__ hBseq, float* __restrict__ decb,
                                              u32* flags) {
  __shared__ short lA[2][16][520];
  __shared__ short lB[2][16][520];
  __shared__ float zt[4][16][20];
  const int tid = threadIdx.x;
  const int wv = tid >> 6, lane = tid & 63;
  const int l15 = lane & 15, l4 = lane >> 4;
  const int gw = blockIdx.x * 4 + wv;
  const int bb = lane >> 2, jj = lane & 3;
  const int hidx = gw * 4 + jj;

  float cAr = c1f[bb * Hq + hidx], cBr = c2f[bb * Hq + hidx];
  {
    float ha = h1f[bb * Hq + hidx], hbv = h2f[bb * Hq + hidx];
    short ahi = f2bf(ha), alo = f2bf(ha - bf2f(ahi));
    short bhi = f2bf(hbv), blo = f2bf(hbv - bf2f(bhi));
    for (int par = 0; par < 2; ++par) {
      size_t o = (size_t)par * 2 * BH + bb * Hq + hidx;
      hAbuf[o] = ahi; hAbuf[o + BH] = alo;
      hBbuf[o] = bhi; hBbuf[o + BH] = blo;
    }
  }
  float bdi = bd2[hidx], bdf = bd2[Hq + hidx], bdg = bd2[2 * Hq + hidx], bdo = bd2[3 * Hq + hidx];
  flagbar(flags, 1);

  const short* u1b = U1T + (size_t)(gw * 16 + l15) * Hq + l4 * 8;
  const short* w2b = W2T + (size_t)(gw * 16 + l15) * Hq + l4 * 8;
  const short* u2b = U2T + (size_t)(gw * 16 + l15) * Hq + l4 * 8;

  for (int p = 0; p <= Tq; ++p) {
    const short* asrc = hAbuf + (size_t)(p & 1) * 2 * BH;
    const short* bsrc = hBbuf + (size_t)(p & 1) * 2 * BH;
    for (int i = tid; i < 2048; i += 256) {
      int part = i >> 10, rem = i & 1023, r = rem >> 6, o = (rem & 63) * 8;
      *(bfrag*)&lA[part][r][o] = *(const bfrag*)&asrc[part * BH + r * Hq + o];
      *(bfrag*)&lB[part][r][o] = *(const bfrag*)&bsrc[part * BH + r * Hq + o];
    }
    __syncthreads();

    facc a0 = {}, a1 = {}, b0 = {}, b1 = {}, b2a = {}, b3 = {};
    if (p < Tq) {
      #pragma unroll
      for (int ks = 0; ks < 16; ++ks) {
        bfrag u = *(const bfrag*)&u1b[ks * 32];
        bfrag ah = *(const bfrag*)&lA[0][l15][ks * 32 + l4 * 8];
        bfrag al = *(const bfrag*)&lA[1][l15][ks * 32 + l4 * 8];
        a0 = __builtin_amdgcn_mfma_f32_16x16x32_bf16(ah, u, a0, 0, 0, 0);
        a1 = __builtin_amdgcn_mfma_f32_16x16x32_bf16(al, u, a1, 0, 0, 0);
      }
    }
    if (p >= 1) {
      #pragma unroll
      for (int ks = 0; ks < 16; ++ks) {
        bfrag w = *(const bfrag*)&w2b[ks * 32];
        bfrag u = *(const bfrag*)&u2b[ks * 32];
        bfrag xh = *(const bfrag*)&lA[0][l15][ks * 32 + l4 * 8];
        bfrag xl = *(const bfrag*)&lA[1][l15][ks * 32 + l4 * 8];
        bfrag hh = *(const bfrag*)&lB[0][l15][ks * 32 + l4 * 8];
        bfrag hl = *(const bfrag*)&lB[1][l15][ks * 32 + l4 * 8];
        b0 = __builtin_amdgcn_mfma_f32_16x16x32_bf16(xh, w, b0, 0, 0, 0);
        b1 = __builtin_amdgcn_mfma_f32_16x16x32_bf16(xl, w, b1, 0, 0, 0);
        b2a = __builtin_amdgcn_mfma_f32_16x16x32_bf16(hh, u, b2a, 0, 0, 0);
        b3 = __builtin_amdgcn_mfma_f32_16x16x32_bf16(hl, u, b3, 0, 0, 0);
      }
    }

    if (p < Tq) {                       // epilogue A -> hA(p)
      a0 += a1;
      *(f32x4*)&zt[wv][l15][l4 * 4] = a0;
      __syncthreads();
      f32x4 xg = *(const f32x4*)&XW[(size_t)(p * Bq + bb) * G4H + hidx * 4];
      float zi = zt[wv][4 * jj + 0][bb] + xg[0];
      float zf = zt[wv][4 * jj + 1][bb] + xg[1];
      float zg = zt[wv][4 * jj + 2][bb] + xg[2];
      float zo = zt[wv][4 * jj + 3][bb] + xg[3];
      cAr = sigm(zf) * cAr + sigm(zi) * tanhf(zg);
      float hN = sigm(zo) * tanhf(cAr);
      short hi_ = f2bf(hN), lo_ = f2bf(hN - bf2f(hi_));
      size_t np = (size_t)((p + 1) & 1) * 2 * BH;
      hAbuf[np + bb * Hq + hidx] = hi_;
      hAbuf[np + BH + bb * Hq + hidx] = lo_;
      __syncthreads();                  // zt reuse guard
    }
    if (p >= 1) {                       // epilogue B -> hB(p-1)
      int s = p - 1;
      b0 += b1; b0 += b2a; b0 += b3;
      *(f32x4*)&zt[wv][l15][l4 * 4] = b0;
      __syncthreads();
      float zi = zt[wv][4 * jj + 0][bb] + bdi;
      float zf = zt[wv][4 * jj + 1][bb] + bdf;
      float zg = zt[wv][4 * jj + 2][bb] + bdg;
      float zo = zt[wv][4 * jj + 3][bb] + bdo;
      cBr = sigm(zf) * cBr + sigm(zi) * tanhf(zg);
      float hN = sigm(zo) * tanhf(cBr);
      short hi_ = f2bf(hN), lo_ = f2bf(hN - bf2f(hi_));
      size_t np = (size_t)((p + 1) & 1) * 2 * BH;
      hBbuf[np + bb * Hq + hidx] = hi_;
      hBbuf[np + BH + bb * Hq + hidx] = lo_;
      hBseq[(size_t)(s * Bq + bb) * Hq + hidx] = hN;
      decb[((size_t)bb * Tq + s) * (2 * Hq) + hidx] = hN;
    }
    flagbar(flags, (u32)(p + 2));
  }
}

// ---------------- batched attention over full seq2 (one block per (b,t))
__global__ __launch_bounds__(256) void k_attn(const float* __restrict__ seq2,
                                              const float* __restrict__ hBseq,
                                              float* __restrict__ dec) {
  int blk = blockIdx.x;
  int b = blk >> 7, t = blk & 127;
  __shared__ float q[Hq];
  __shared__ float part[256];
  __shared__ float p[Tq];
  int tid = threadIdx.x;
  const float* qsrc = hBseq + (size_t)(t * Bq + b) * Hq;
  q[tid] = qsrc[tid]; q[tid + 256] = qsrc[tid + 256];
  __syncthreads();
  {
    int s = tid >> 1, half = tid & 1;
    const float* row = seq2 + (size_t)(s * Bq + b) * Hq + half * 256;
    const float* qh = q + half * 256;
    float a = 0.0f;
    for (int k = 0; k < 256; k += 4) {
      f32x4 r4 = *(const f32x4*)(row + k);
      f32x4 q4 = *(const f32x4*)(qh + k);
      a += r4[0] * q4[0] + r4[1] * q4[1] + r4[2] * q4[2] + r4[3] * q4[3];
    }
    part[tid] = a;
  }
  __syncthreads();
  if (tid < 64) {
    float v0 = part[2 * tid] + part[2 * tid + 1];
    float v1 = part[2 * (tid + 64)] + part[2 * (tid + 64) + 1];
    float mx = fmaxf(v0, v1);
    for (int off = 32; off; off >>= 1) mx = fmaxf(mx, __shfl_xor(mx, off));
    float e0 = __expf(v0 - mx), e1 = __expf(v1 - mx);
    float sm = e0 + e1;
    for (int off = 32; off; off >>= 1) sm += __shfl_xor(sm, off);
    float inv = 1.0f / sm;
    p[tid] = e0 * inv; p[tid + 64] = e1 * inv;
  }
  __syncthreads();
  float c0 = 0.0f, c1 = 0.0f;
  for (int s = 0; s < Tq; ++s) {
    float ps = p[s];
    const float* row = seq2 + (size_t)(s * Bq + b) * Hq;
    c0 += ps * row[tid];
    c1 += ps * row[tid + 256];
  }
  float* drow = dec + (size_t)(b * Tq + t) * (2 * Hq) + Hq;
  drow[tid] = c0; drow[tid + 256] = c1;
}

// ---------------- row softmax over VO=32001 (in-place on d_out)
__global__ __launch_bounds__(256) void k_softmax(float* __restrict__ L) {
  int row = blockIdx.x;
  float* p = L + (size_t)row * VO;
  int tid = threadIdx.x;
  float m = -3.0e38f, s = 0.0f;
  for (int i = tid; i < VO; i += 256) {
    float v = p[i];
    float mn = fmaxf(m, v);
    s = s * __expf(m - mn) + __expf(v - mn);
    m = mn;
  }
  __shared__ float sm[256], ss[256];
  sm[tid] = m; ss[tid] = s;
  __syncthreads();
  for (int off = 128; off; off >>= 1) {
    if (tid < off) {
      float m2 = sm[tid + off], s2 = ss[tid + off];
      float mn = fmaxf(sm[tid], m2);
      ss[tid] = ss[tid] * __expf(sm[tid] - mn) + s2 * __expf(m2 - mn);
      sm[tid] = mn;
    }
    __syncthreads();
  }
  float M = sm[0], IS = 1.0f / ss[0];
  for (int i = tid; i < VO; i += 256) {
    p[i] = __expf(p[i] - M) * IS;
  }
}

// =============================================================================
extern "C" void kernel_launch(void* const* d_in, const int* in_sizes, int n_in,
                              void* d_out, int out_size, void* d_ws, size_t ws_size,
                              hipStream_t stream) {
  const int*   tokens = (const int*)d_in[0];
  const float* emb    = (const float*)d_in[1];
  const float* W1     = (const float*)d_in[2];
  const float* U1     = (const float*)d_in[3];
  const float* b1     = (const float*)d_in[4];
  const float* W2     = (const float*)d_in[5];
  const float* U2     = (const float*)d_in[6];
  const float* b2     = (const float*)d_in[7];
  const float* Wd1    = (const float*)d_in[8];
  const float* Ud1    = (const float*)d_in[9];
  const float* bd1    = (const float*)d_in[10];
  const float* Wd2    = (const float*)d_in[11];
  const float* Ud2    = (const float*)d_in[12];
  const float* bd2    = (const float*)d_in[13];
  const float* Wo     = (const float*)d_in[14];
  const float* bo     = (const float*)d_in[15];
  float* out = (float*)d_out;

  size_t off = 0;
  char* base = (char*)d_ws;
  auto alloc = [&](size_t bytes) -> void* {
    void* p = base + off;
    off += (bytes + 255) & ~(size_t)255;
    return p;
  };
  u32*   flags   = (u32*)alloc(3 * 4096);
  short* x_bf    = (short*)alloc((size_t)MR * Dq * 2);
  short* W1T     = (short*)alloc((size_t)G4H * Dq * 2);
  short* W2T     = (short*)alloc((size_t)G4H * Hq * 2);
  short* Wd1T    = (short*)alloc((size_t)G4H * Hq * 2);
  short* WoT     = (short*)alloc((size_t)NPAD * (2 * Hq) * 2);
  short* U1T     = (short*)alloc((size_t)G4H * Hq * 2);
  short* U2T     = (short*)alloc((size_t)G4H * Hq * 2);
  short* Ud1T    = (short*)alloc((size_t)G4H * Hq * 2);
  short* Ud2T    = (short*)alloc((size_t)G4H * Hq * 2);
  short* Wd2T    = (short*)alloc((size_t)G4H * Hq * 2);
  float* XW      = (float*)alloc((size_t)MR * G4H * 4);       // reused x3
  short* seq1_bf = (short*)alloc((size_t)MR * Hq * 2);
  short* seq2_bf = (short*)alloc((size_t)MR * Hq * 2);
  float* seq2    = (float*)alloc((size_t)MR * Hq * 4);
  float* hBseq   = (float*)alloc((size_t)MR * Hq * 4);
  float* dec     = (float*)alloc((size_t)MR * 2 * Hq * 4);
  short* dec_bf  = (short*)alloc((size_t)MR * 2 * Hq * 2);
  short* h1buf   = (short*)alloc((size_t)4 * BH * 2);
  short* h2buf   = (short*)alloc((size_t)4 * BH * 2);
  short* hAbuf   = (short*)alloc((size_t)4 * BH * 2);
  short* hBbuf   = (short*)alloc((size_t)4 * BH * 2);
  float* h1f = (float*)alloc(BH * 4);
  float* c1f = (float*)alloc(BH * 4);
  float* h2f = (float*)alloc(BH * 4);
  float* c2f = (float*)alloc(BH * 4);
  u32* flags0 = flags;
  u32* flags1 = flags + 1024;
  u32* flags2 = flags + 2048;
  (void)ws_size; (void)in_sizes; (void)n_in; (void)out_size;

  hipMemsetAsync(flags, 0, 3 * 4096, stream);

  // weight transposes + bf16 conversion (+ gate-interleave perm on recurrent mats)
  k_transcvt<<<dim3(G4H / 32, Dq / 32), 256, 0, stream>>>(W1, W1T, Dq, G4H, 1);
  k_transcvt<<<dim3(G4H / 32, Hq / 32), 256, 0, stream>>>(W2, W2T, Hq, G4H, 1);
  k_transcvt<<<dim3(G4H / 32, Hq / 32), 256, 0, stream>>>(Wd1, Wd1T, Hq, G4H, 1);
  k_transcvt<<<dim3(G4H / 32, Hq / 32), 256, 0, stream>>>(U1, U1T, Hq, G4H, 1);
  k_transcvt<<<dim3(G4H / 32, Hq / 32), 256, 0, stream>>>(U2, U2T, Hq, G4H, 1);
  k_transcvt<<<dim3(G4H / 32, Hq / 32), 256, 0, stream>>>(Ud1, Ud1T, Hq, G4H, 1);
  k_transcvt<<<dim3(G4H / 32, Hq / 32), 256, 0, stream>>>(Ud2, Ud2T, Hq, G4H, 1);
  k_transcvt<<<dim3(G4H / 32, Hq / 32), 256, 0, stream>>>(Wd2, Wd2T, Hq, G4H, 1);
  k_transcvt<<<dim3(NPAD / 32, (2 * Hq) / 32), 256, 0, stream>>>(Wo, WoT, 2 * Hq, VO, 0);

  k_gather<<<MR, 256, 0, stream>>>(tokens, emb, x_bf);

  // encoder layer 1
  k_gemm<<<dim3(G4H / 128, MR / 128), 256, 0, stream>>>(x_bf, W1T, XW, b1, MR, G4H, Dq, G4H, 1);
  k_rec<<<NBLK, 256, 0, stream>>>(XW, U1T, nullptr, nullptr, h1buf, h1f, c1f, seq1_bf, nullptr, flags0);

  // encoder layer 2 (init from layer-1 finals)
  k_gemm<<<dim3(G4H / 128, MR / 128), 256, 0, stream>>>(seq1_bf, W2T, XW, b2, MR, G4H, Hq, G4H, 1);
  k_rec<<<NBLK, 256, 0, stream>>>(XW, U2T, h1f, c1f, h2buf, h2f, c2f, seq2_bf, seq2, flags1);

  // decoder (cells A,B skewed)
  k_gemm<<<dim3(G4H / 128, MR / 128), 256, 0, stream>>>(seq2_bf, Wd1T, XW, bd1, MR, G4H, Hq, G4H, 1);
  k_dec2<<<NBLK, 256, 0, stream>>>(XW, Ud1T, Wd2T, Ud2T, bd2, h1f, c1f, h2f, c2f,
                                   hAbuf, hBbuf, hBseq, dec, flags2);

  // attention + logits + softmax
  k_attn<<<MR, 256, 0, stream>>>(seq2, hBseq, dec);
  k_cvt<<<(MR * 2 * Hq) / 1024, 256, 0, stream>>>(dec, dec_bf, MR * 2 * Hq);
  k_gemm<<<dim3(NPAD / 128, MR / 128), 256, 0, stream>>>(dec_bf, WoT, out, bo, MR, VO, 2 * Hq, VO, 0);
  k_softmax<<<MR, 256, 0, stream>>>(out);
}